// Round 1
// baseline (32.961 us; speedup 1.0000x reference)
//
#include <hip/hip_runtime.h>
#include <math.h>

// Cox partial-likelihood loss, N = 16384.
//   T = |y|, E = (y > 0), theta = y_hat, e = exp(theta)
//   risk[i] = sum_j e[j] * (T[j] >= T[i])
//   loss = -mean((theta - log(risk)) * E)
//
// ws layout: float2 pairs[N]  (T, e)   : N*8 bytes
//            float  risk[N]            : N*4 bytes

#define BLK 256
#define JCHUNK 1024

// ---------------- Kernel A: precompute pairs, zero risk + out ----------------
__global__ void cox_init(const float* __restrict__ y_hat,
                         const float* __restrict__ y,
                         float2* __restrict__ pairs,
                         float* __restrict__ risk,
                         float* __restrict__ out,
                         int n) {
    int i = blockIdx.x * blockDim.x + threadIdx.x;
    if (i < n) {
        float t = fabsf(y[i]);
        float e = expf(y_hat[i]);
        pairs[i] = make_float2(t, e);
        risk[i] = 0.0f;
    }
    if (i == 0) out[0] = 0.0f;
}

// ---------------- Kernel B: risk_sum partial over j-chunks ----------------
// grid = (n/BLK, n/JCHUNK); each block: 256 i's  x  1024 j's
__global__ void __launch_bounds__(BLK) cox_risk(
        const float* __restrict__ y,
        const float2* __restrict__ pairs,
        float* __restrict__ risk,
        int n) {
    __shared__ float2 sp[JCHUNK];

    const int i = blockIdx.x * BLK + threadIdx.x;
    const float Ti = fabsf(y[i]);

    const int j0 = blockIdx.y * JCHUNK;
    // stage chunk into LDS (coalesced float2 loads)
    #pragma unroll
    for (int k = threadIdx.x; k < JCHUNK; k += BLK) {
        sp[k] = pairs[j0 + k];
    }
    __syncthreads();

    float acc = 0.0f;
    #pragma unroll 8
    for (int k = 0; k < JCHUNK; ++k) {
        float2 p = sp[k];            // wave-uniform address -> LDS broadcast
        acc += (p.x >= Ti) ? p.y : 0.0f;
    }

    atomicAdd(&risk[i], acc);
}

// ---------------- Kernel C: loss reduction ----------------
__global__ void __launch_bounds__(BLK) cox_loss(
        const float* __restrict__ y_hat,
        const float* __restrict__ y,
        const float* __restrict__ risk,
        float* __restrict__ out,
        int n) {
    __shared__ float warp_part[BLK / 64];

    int i = blockIdx.x * blockDim.x + threadIdx.x;
    float term = 0.0f;
    if (i < n) {
        float E = (y[i] > 0.0f) ? 1.0f : 0.0f;
        term = (y_hat[i] - logf(risk[i])) * E;
    }

    // wave-64 butterfly reduce
    #pragma unroll
    for (int off = 32; off > 0; off >>= 1) {
        term += __shfl_down(term, off, 64);
    }
    int lane = threadIdx.x & 63;
    int wid = threadIdx.x >> 6;
    if (lane == 0) warp_part[wid] = term;
    __syncthreads();

    if (threadIdx.x == 0) {
        float s = 0.0f;
        #pragma unroll
        for (int w = 0; w < BLK / 64; ++w) s += warp_part[w];
        atomicAdd(out, -s / (float)n);
    }
}

extern "C" void kernel_launch(void* const* d_in, const int* in_sizes, int n_in,
                              void* d_out, int out_size, void* d_ws, size_t ws_size,
                              hipStream_t stream) {
    const float* y_hat = (const float*)d_in[0];
    const float* y     = (const float*)d_in[1];
    float* out = (float*)d_out;
    const int n = in_sizes[0];   // 16384

    float2* pairs = (float2*)d_ws;
    float*  risk  = (float*)((char*)d_ws + (size_t)n * sizeof(float2));

    const int nblk = (n + BLK - 1) / BLK;

    cox_init<<<nblk, BLK, 0, stream>>>(y_hat, y, pairs, risk, out, n);

    dim3 gridB(n / BLK, n / JCHUNK);   // (64, 16)
    cox_risk<<<gridB, BLK, 0, stream>>>(y, pairs, risk, n);

    cox_loss<<<nblk, BLK, 0, stream>>>(y_hat, y, risk, out, n);
}